// Round 3
// baseline (141.730 us; speedup 1.0000x reference)
//
#include <hip/hip_runtime.h>

#define HH_DIM 2048
#define WW_DIM 2048
#define NF 64
#define MAX_DEPTH 12
#define MAX_ITEMS 32768

// Node / item encoding: word0 = x0 | y0<<11 | idx<<22 ; word1 = w | h<<12
__device__ __forceinline__ uint2 enc(int x0, int y0, int idx, int w, int h) {
    return make_uint2((unsigned)x0 | ((unsigned)y0 << 11) | ((unsigned)idx << 22),
                      (unsigned)w | ((unsigned)h << 12));
}

__device__ __forceinline__ unsigned wave_iscan(unsigned x, int lane) {
    #pragma unroll
    for (int off = 1; off < 64; off <<= 1) {
        unsigned v = __shfl_up(x, off);
        if (lane >= off) x += v;
    }
    return x;
}

__device__ __forceinline__ int calc_nit(int w, int h) {
    int rpc = 1024 / w; if (rpc < 1) rpc = 1;
    return (h + rpc - 1) / rpc;
}

// Emit row-chunk items for a leaf rect; returns next slot.
__device__ __forceinline__ int emit_rect(uint2* __restrict__ items, int s,
                                         int x0, int y0, int w, int h, int idx) {
    int rpc = 1024 / w; if (rpc < 1) rpc = 1;
    int nit = (h + rpc - 1) / rpc;
    for (int k = 0; k < nit; ++k) {
        int r0 = k * rpc;
        int hc = h - r0; if (hc > rpc) hc = rpc;
        if (s < MAX_ITEMS) items[s] = enc(x0, y0 + r0, idx, w, hc);
        ++s;
    }
    return s;
}

// Kernel A: argmax + BFS leaf decomposition (single workgroup).
__global__ __launch_bounds__(256)
void build_kernel(const float* __restrict__ sel,     // [NF,2,NF]
                  const float* __restrict__ ratios,  // [NF]
                  const float* __restrict__ colors,  // [NF,3]
                  float4* __restrict__ cpack,        // ws+0     [NF]
                  int* __restrict__ item_count,      // ws+1024
                  uint2* __restrict__ items) {       // ws+1088  [MAX_ITEMS]
    __shared__ float s_ratio[NF];
    __shared__ int   s_child[2 * NF];
    __shared__ uint2 s_nodes[2][2048];   // levels 0..11 only (<=2048 nodes)
    __shared__ int   s_cnt[2];
    __shared__ int   s_items;

    int t = threadIdx.x;
    int lane = t & 63, wid = t >> 6;

    if (t < 2 * NF) {                     // first-max argmax (strict >)
        const float* row = sel + t * NF;
        float best = row[0]; int bi = 0;
        #pragma unroll
        for (int j = 1; j < NF; ++j) { float v = row[j]; if (v > best) { best = v; bi = j; } }
        s_child[t] = bi;
    }
    if (t < NF) {
        s_ratio[t] = ratios[t];
        cpack[t] = make_float4(colors[3*t], colors[3*t+1], colors[3*t+2], 0.0f);
    }
    if (t == 0) {
        s_cnt[0] = 1; s_cnt[1] = 0; s_items = 0;
        s_nodes[0][0] = enc(0, 0, 0, WW_DIM, HH_DIM);
    }
    __syncthreads();

    for (int d = 0; d < MAX_DEPTH; ++d) {          // depth-12 children emitted at d==11
        int cur = d & 1, nx = cur ^ 1;
        int n = s_cnt[cur];
        bool last = (d == MAX_DEPTH - 1);
        for (int base = wid * 64; base < n; base += 256) {
            int i = base + lane;
            bool valid = i < n;
            int x0 = 0, y0 = 0, idx = 0, w = 1, h = 1;
            bool split = false;
            if (valid) {
                uint2 nd = s_nodes[cur][i];
                x0 = nd.x & 0x7FF; y0 = (nd.x >> 11) & 0x7FF; idx = (int)(nd.x >> 22);
                w = nd.y & 0xFFF;  h = (nd.y >> 12) & 0xFFF;
                split = (w >= 2) && (h >= 2);
            }
            // Child geometry (needed for both append and last-level emission).
            int lw = 1, lx0 = x0, ly0 = y0, lwid = w, lhgt = h,
                rx0 = x0, ry0 = y0, rwid = w, rhgt = h, lc = 0, rc = 0;
            if (valid && split) {
                float ratio = s_ratio[idx];
                lc = s_child[2 * idx]; rc = s_child[2 * idx + 1];
                if (idx & 1) {                       // vertical split
                    lw = (int)floorf((float)w * ratio); if (lw < 1) lw = 1;
                    lwid = lw;          rhgt = h;
                    rx0 = x0 + lw;      rwid = w - lw;
                } else {                             // horizontal split
                    lw = (int)floorf((float)h * ratio); if (lw < 1) lw = 1;
                    lhgt = lw;
                    ry0 = y0 + lw;      rhgt = h - lw;
                }
            }
            unsigned nchild = 0, nit = 0;
            if (valid) {
                if (split && !last) nchild = 2;
                else if (split && last)               // children are depth-12 leaves
                    nit = (unsigned)(calc_nit(lwid, lhgt) + calc_nit(rwid, rhgt));
                else
                    nit = (unsigned)calc_nit(w, h);
            }
            unsigned incC = wave_iscan(nchild, lane);
            unsigned incI = wave_iscan(nit, lane);
            unsigned totC = __shfl(incC, 63);
            unsigned totI = __shfl(incI, 63);
            int bC = 0, bI = 0;
            if (lane == 63) {
                if (totC) bC = atomicAdd(&s_cnt[nx], (int)totC);
                if (totI) bI = atomicAdd(&s_items, (int)totI);
            }
            bC = __shfl(bC, 63);
            bI = __shfl(bI, 63);
            int cslot = bC + (int)(incC - nchild);
            int islot = bI + (int)(incI - nit);

            if (valid && nchild) {
                s_nodes[nx][cslot]     = enc(lx0, ly0, lc, lwid, lhgt);
                s_nodes[nx][cslot + 1] = enc(rx0, ry0, rc, rwid, rhgt);
            }
            if (valid && nit) {
                int s = islot;
                if (split) {                          // last level, split node
                    s = emit_rect(items, s, lx0, ly0, lwid, lhgt, lc);
                    s = emit_rect(items, s, rx0, ry0, rwid, rhgt, rc);
                } else {
                    s = emit_rect(items, s, x0, y0, w, h, idx);
                }
            }
        }
        __syncthreads();
        if (t == 0) s_cnt[cur] = 0;
        __syncthreads();
    }
    if (t == 0) *item_count = (s_items < MAX_ITEMS) ? s_items : MAX_ITEMS;
}

// Kernel B: fill each row-chunk item with its color. Pure stores, no LDS.
__global__ __launch_bounds__(256)
void fill_kernel(const float4* __restrict__ cpack,
                 const int* __restrict__ item_count,
                 const uint2* __restrict__ items,
                 float* __restrict__ out) {           // [3,H,W]
    const int plane = HH_DIM * WW_DIM;
    int count = *item_count;
    for (int it = blockIdx.x; it < count; it += gridDim.x) {
        uint2 v = items[it];
        int x0 = v.x & 0x7FF, y0 = (v.x >> 11) & 0x7FF, idx = (int)(v.x >> 22);
        int w = v.y & 0xFFF,  hc = (int)((v.y >> 12) & 0xFFF);
        float4 col = cpack[idx];
        int n = w * hc;                               // <= 2048
        float rw = 1.0f / (float)w;
        for (int p = threadIdx.x; p < n; p += 256) {
            int r = (int)((float)p * rw);             // +-1 accurate, fixed below
            int c = p - r * w;
            if (c < 0)       { r -= 1; c += w; }
            else if (c >= w) { r += 1; c -= w; }
            int off = (y0 + r) * WW_DIM + x0 + c;
            out[off]             = col.x;
            out[plane + off]     = col.y;
            out[2 * plane + off] = col.z;
        }
    }
}

extern "C" void kernel_launch(void* const* d_in, const int* in_sizes, int n_in,
                              void* d_out, int out_size, void* d_ws, size_t ws_size,
                              hipStream_t stream) {
    const float* frame_colors    = (const float*)d_in[0];  // [64,3]
    const float* frame_selection = (const float*)d_in[1];  // [64,2,64]
    const float* split_ratios    = (const float*)d_in[2];  // [64]
    float* out = (float*)d_out;

    float4* cpack   = (float4*)d_ws;                       // 1024 B
    int*    count   = (int*)((char*)d_ws + 1024);
    uint2*  items   = (uint2*)((char*)d_ws + 1088);        // 256 KB

    build_kernel<<<1, 256, 0, stream>>>(frame_selection, split_ratios,
                                        frame_colors, cpack, count, items);
    fill_kernel<<<4096, 256, 0, stream>>>(cpack, count, items, out);
}

// Round 4
// 140.888 us; speedup vs baseline: 1.0060x; 1.0060x over previous
//
#include <hip/hip_runtime.h>

#define HH_DIM 2048
#define WW_DIM 2048
#define NF 64
#define MAX_DEPTH 12
#define NSLOTS 8191          // complete binary tree, levels 0..12
#define L12_OFF 4095         // offset of level-12 slots
#define MAX_ITEMS 32768

// Node / item encoding:
//   word0 = x0 | y0<<12 | idx<<24   (x0,y0 <= 2047; idx <= 63)
//   word1 = w | h<<12               (w,h <= 2048; word1==0 => inactive)
__device__ __forceinline__ uint2 enc(int x0, int y0, int idx, int w, int h) {
    return make_uint2((unsigned)x0 | ((unsigned)y0 << 12) | ((unsigned)idx << 24),
                      (unsigned)w | ((unsigned)h << 12));
}

__device__ __forceinline__ unsigned wave_iscan(unsigned x, int lane) {
    #pragma unroll
    for (int off = 1; off < 64; off <<= 1) {
        unsigned v = __shfl_up(x, off);
        if (lane >= off) x += v;
    }
    return x;
}

__device__ __forceinline__ int calc_nit(int w, int h) {
    int rpc = 1024 / w; if (rpc < 1) rpc = 1;     // rows per chunk
    return (h + rpc - 1) / rpc;
}

// Kernel A: argmax + slot-addressed BFS (no scans/atomics in the descent)
// + one compacted item-emission pass. Single workgroup, but every level is
// straight-line parallel work: read parent slot, write two child slots.
__global__ __launch_bounds__(256)
void build_kernel(const float* __restrict__ sel,     // [NF,2,NF]
                  const float* __restrict__ ratios,  // [NF]
                  const float* __restrict__ colors,  // [NF,3]
                  float4* __restrict__ cpack,        // ws+0     [NF]
                  int* __restrict__ item_count,      // ws+1024
                  uint2* __restrict__ items) {       // ws+1088  [MAX_ITEMS]
    __shared__ float s_ratio[NF];
    __shared__ int   s_child[2 * NF];
    __shared__ uint2 s_tree[NSLOTS];                 // 64 KB
    __shared__ int   s_items;

    int t = threadIdx.x;
    int lane = t & 63;

    if (t < 2 * NF) {                     // first-max argmax (strict >)
        const float* row = sel + t * NF;
        float best = row[0]; int bi = 0;
        #pragma unroll
        for (int j = 1; j < NF; ++j) { float v = row[j]; if (v > best) { best = v; bi = j; } }
        s_child[t] = bi;
    }
    if (t < NF) {
        s_ratio[t] = ratios[t];
        cpack[t] = make_float4(colors[3*t], colors[3*t+1], colors[3*t+2], 0.0f);
    }
    if (t == 0) {
        s_items = 0;
        s_tree[0] = enc(0, 0, 0, WW_DIM, HH_DIM);
    }
    __syncthreads();

    // BFS: level d (2^d nodes at offset 2^d-1) -> level d+1.
    int off = 0;
    for (int d = 0; d < MAX_DEPTH; ++d) {
        int n = 1 << d;
        int coff = off + n;
        for (int k = t; k < n; k += 256) {
            uint2 nd = s_tree[off + k];
            int w = (int)(nd.y & 0xFFF), h = (int)((nd.y >> 12) & 0xFFF);
            uint2 cl = make_uint2(0u, 0u), cr = make_uint2(0u, 0u);
            if (w >= 2 && h >= 2) {                  // active split node
                int x0 = (int)(nd.x & 0xFFF), y0 = (int)((nd.x >> 12) & 0xFFF);
                int idx = (int)(nd.x >> 24);
                float ratio = s_ratio[idx];
                int lc = s_child[2 * idx], rc = s_child[2 * idx + 1];
                if (idx & 1) {                       // vertical split
                    int lw = (int)floorf((float)w * ratio); if (lw < 1) lw = 1;
                    cl = enc(x0,      y0, lc, lw,     h);
                    cr = enc(x0 + lw, y0, rc, w - lw, h);
                } else {                             // horizontal split
                    int th = (int)floorf((float)h * ratio); if (th < 1) th = 1;
                    cl = enc(x0, y0,      lc, w, th);
                    cr = enc(x0, y0 + th, rc, w, h - th);
                }
            }
            s_tree[coff + 2 * k]     = cl;           // inactive propagates 0
            s_tree[coff + 2 * k + 1] = cr;
        }
        off = coff;
        __syncthreads();
    }

    // Emission: leaves = active slots with (w<2 || h<2), or any active
    // level-12 slot (depth cap). Compact into row-chunk items.
    for (int base = 0; base < NSLOTS; base += 256) {
        int i = base + t;
        unsigned nit = 0;
        int x0 = 0, y0 = 0, idx = 0, w = 1, h = 1;
        bool leaf = false;
        if (i < NSLOTS) {
            uint2 nd = s_tree[i];
            if (nd.y != 0u) {
                w = (int)(nd.y & 0xFFF); h = (int)((nd.y >> 12) & 0xFFF);
                leaf = (i >= L12_OFF) || (w < 2) || (h < 2);
                if (leaf) {
                    x0 = (int)(nd.x & 0xFFF); y0 = (int)((nd.x >> 12) & 0xFFF);
                    idx = (int)(nd.x >> 24);
                    nit = (unsigned)calc_nit(w, h);
                }
            }
        }
        if (__ballot(nit != 0) == 0ULL) continue;    // wave-uniform skip
        unsigned inc = wave_iscan(nit, lane);
        unsigned tot = __shfl(inc, 63);
        int b = 0;
        if (lane == 63) b = atomicAdd(&s_items, (int)tot);
        b = __shfl(b, 63);
        int s = b + (int)(inc - nit);
        if (leaf) {
            int rpc = 1024 / w; if (rpc < 1) rpc = 1;
            int nn = (int)nit;
            for (int k = 0; k < nn; ++k) {
                int r0 = k * rpc;
                int hc = h - r0; if (hc > rpc) hc = rpc;
                if (s + k < MAX_ITEMS) items[s + k] = enc(x0, y0 + r0, idx, w, hc);
            }
        }
    }
    __syncthreads();
    if (t == 0) *item_count = (s_items < MAX_ITEMS) ? s_items : MAX_ITEMS;
}

// Kernel B: fill each row-chunk item with its color. Pure coalesced stores.
__global__ __launch_bounds__(256)
void fill_kernel(const float4* __restrict__ cpack,
                 const int* __restrict__ item_count,
                 const uint2* __restrict__ items,
                 float* __restrict__ out) {           // [3,H,W]
    const int plane = HH_DIM * WW_DIM;
    int count = *item_count;
    for (int it = blockIdx.x; it < count; it += gridDim.x) {
        uint2 v = items[it];
        int x0 = (int)(v.x & 0xFFF), y0 = (int)((v.x >> 12) & 0xFFF);
        int idx = (int)(v.x >> 24);
        int w = (int)(v.y & 0xFFF), hc = (int)((v.y >> 12) & 0xFFF);
        float4 col = cpack[idx];
        int n = w * hc;                               // <= ~2048
        float rw = 1.0f / (float)w;
        for (int p = threadIdx.x; p < n; p += 256) {
            int r = (int)((float)p * rw);             // +-1, fixed below
            int c = p - r * w;
            if (c < 0)       { r -= 1; c += w; }
            else if (c >= w) { r += 1; c -= w; }
            int off = (y0 + r) * WW_DIM + x0 + c;
            out[off]             = col.x;
            out[plane + off]     = col.y;
            out[2 * plane + off] = col.z;
        }
    }
}

extern "C" void kernel_launch(void* const* d_in, const int* in_sizes, int n_in,
                              void* d_out, int out_size, void* d_ws, size_t ws_size,
                              hipStream_t stream) {
    const float* frame_colors    = (const float*)d_in[0];  // [64,3]
    const float* frame_selection = (const float*)d_in[1];  // [64,2,64]
    const float* split_ratios    = (const float*)d_in[2];  // [64]
    float* out = (float*)d_out;

    float4* cpack = (float4*)d_ws;                         // 1024 B
    int*    count = (int*)((char*)d_ws + 1024);
    uint2*  items = (uint2*)((char*)d_ws + 1088);          // 256 KB

    build_kernel<<<1, 256, 0, stream>>>(frame_selection, split_ratios,
                                        frame_colors, cpack, count, items);
    fill_kernel<<<4096, 256, 0, stream>>>(cpack, count, items, out);
}

// Round 5
// 109.961 us; speedup vs baseline: 1.2889x; 1.2813x over previous
//
#include <hip/hip_runtime.h>

#define HH_DIM 2048
#define WW_DIM 2048
#define NF 64
#define MAX_DEPTH 12
#define NBLK 16            // build blocks; each owns 256 of the 4096 paths
#define SEG 8192           // items per block segment (safe upper bound)

// Item encoding:
//   word0 = x0 | y0<<12 | idx<<24   (x0,y0 <= 2047; idx <= 63)
//   word1 = w | h<<12               (w,h <= 2048)
__device__ __forceinline__ uint2 enc(int x0, int y0, int idx, int w, int h) {
    return make_uint2((unsigned)x0 | ((unsigned)y0 << 12) | ((unsigned)idx << 24),
                      (unsigned)w | ((unsigned)h << 12));
}

__device__ __forceinline__ unsigned wave_iscan(unsigned x, int lane) {
    #pragma unroll
    for (int off = 1; off < 64; off <<= 1) {
        unsigned v = __shfl_up(x, off);
        if (lane >= off) x += v;
    }
    return x;
}

// Kernel A: path-parallel leaf enumeration. Thread j (j = 0..4095) descends
// the 12-bit path j from the root. Leaf-propagation rule: when the current
// node is a leaf (w<2 || h<2), it "continues" only along the all-left
// extension, so each original leaf stays alive in exactly one thread; all
// depth-12 survivors are emitted. No BFS, no shared tree, no cross-block
// coordination: block b compacts its items into segment b with count cnt[b].
__global__ __launch_bounds__(256)
void build_kernel(const float* __restrict__ sel,     // [NF,2,NF]
                  const float* __restrict__ ratios,  // [NF]
                  const float* __restrict__ colors,  // [NF,3]
                  float4* __restrict__ cpack,        // ws+0     [NF]
                  int* __restrict__ cnt,             // ws+1024  [NBLK]
                  uint2* __restrict__ items) {       // ws+1088  [NBLK*SEG]
    __shared__ float s_ratio[NF];
    __shared__ int   s_child[2 * NF];
    __shared__ int   s_items;

    int t = threadIdx.x;
    int lane = t & 63;

    if (t < 2 * NF) {                     // first-max argmax (strict >)
        const float* row = sel + t * NF;
        float best = row[0]; int bi = 0;
        #pragma unroll
        for (int j = 1; j < NF; ++j) { float v = row[j]; if (v > best) { best = v; bi = j; } }
        s_child[t] = bi;
    }
    if (t < NF) {
        s_ratio[t] = ratios[t];
        if (blockIdx.x == 0)
            cpack[t] = make_float4(colors[3*t], colors[3*t+1], colors[3*t+2], 0.0f);
    }
    if (t == 0) s_items = 0;
    __syncthreads();

    int j = (blockIdx.x << 8) + t;        // path id, 0..4095
    int x0 = 0, y0 = 0, w = WW_DIM, h = HH_DIM, idx = 0;
    bool alive = true;
    #pragma unroll
    for (int d = 0; d < MAX_DEPTH; ++d) {
        int bit = (j >> (11 - d)) & 1;
        if (w < 2 || h < 2) {             // leaf: survives only all-left
            if (bit) { alive = false; break; }
            continue;
        }
        float ratio = s_ratio[idx];
        if (idx & 1) {                    // vertical split
            int lw = (int)floorf((float)w * ratio); if (lw < 1) lw = 1;
            if (bit == 0) { w = lw; } else { x0 += lw; w -= lw; }
        } else {                          // horizontal split
            int th = (int)floorf((float)h * ratio); if (th < 1) th = 1;
            if (bit == 0) { h = th; } else { y0 += th; h -= th; }
        }
        idx = bit ? s_child[2 * idx + 1] : s_child[2 * idx];
    }

    // Row-chunk item count for this thread's rect (chunks of ~1024 px).
    unsigned nit = 0;
    int rpc = 1;
    if (alive) {
        rpc = 1024 / w; if (rpc < 1) rpc = 1;
        nit = (unsigned)((h + rpc - 1) / rpc);
    }

    // Wave-local compaction into the block's segment.
    unsigned inc = wave_iscan(nit, lane);
    unsigned tot = __shfl(inc, 63);
    int base = 0;
    if (lane == 63 && tot) base = atomicAdd(&s_items, (int)tot);
    base = __shfl(base, 63);
    int s = base + (int)(inc - nit);

    uint2* seg = items + blockIdx.x * SEG;
    if (nit) {
        int nn = (int)nit;
        for (int k = 0; k < nn; ++k) {
            int r0 = k * rpc;
            int hc = h - r0; if (hc > rpc) hc = rpc;
            if (s + k < SEG) seg[s + k] = enc(x0, y0 + r0, idx, w, hc);
        }
    }
    __syncthreads();
    if (t == 0) cnt[blockIdx.x] = (s_items < SEG) ? s_items : SEG;
}

// Kernel B: fill each row-chunk item with its color. Pure coalesced stores.
__global__ __launch_bounds__(256)
void fill_kernel(const float4* __restrict__ cpack,
                 const int* __restrict__ cnt,        // [NBLK]
                 const uint2* __restrict__ items,    // [NBLK*SEG]
                 float* __restrict__ out) {          // [3,H,W]
    const int plane = HH_DIM * WW_DIM;
    for (int slot = blockIdx.x; slot < NBLK * SEG; slot += gridDim.x) {
        int sg = slot / SEG, li = slot - sg * SEG;
        if (li >= cnt[sg]) continue;
        uint2 v = items[slot];
        int x0 = (int)(v.x & 0xFFF), y0 = (int)((v.x >> 12) & 0xFFF);
        int idx = (int)(v.x >> 24);
        int w = (int)(v.y & 0xFFF), hc = (int)((v.y >> 12) & 0xFFF);
        float4 col = cpack[idx];
        int n = w * hc;                               // <= ~2048
        float rw = 1.0f / (float)w;
        for (int p = threadIdx.x; p < n; p += 256) {
            int r = (int)((float)p * rw);             // +-1, fixed below
            int c = p - r * w;
            if (c < 0)       { r -= 1; c += w; }
            else if (c >= w) { r += 1; c -= w; }
            int off = (y0 + r) * WW_DIM + x0 + c;
            out[off]             = col.x;
            out[plane + off]     = col.y;
            out[2 * plane + off] = col.z;
        }
    }
}

extern "C" void kernel_launch(void* const* d_in, const int* in_sizes, int n_in,
                              void* d_out, int out_size, void* d_ws, size_t ws_size,
                              hipStream_t stream) {
    const float* frame_colors    = (const float*)d_in[0];  // [64,3]
    const float* frame_selection = (const float*)d_in[1];  // [64,2,64]
    const float* split_ratios    = (const float*)d_in[2];  // [64]
    float* out = (float*)d_out;

    float4* cpack = (float4*)d_ws;                         // 1024 B
    int*    cnt   = (int*)((char*)d_ws + 1024);            // 64 B
    uint2*  items = (uint2*)((char*)d_ws + 1088);          // 1 MB

    build_kernel<<<NBLK, 256, 0, stream>>>(frame_selection, split_ratios,
                                           frame_colors, cpack, cnt, items);
    fill_kernel<<<4096, 256, 0, stream>>>(cpack, cnt, items, out);
}

// Round 6
// 100.081 us; speedup vs baseline: 1.4161x; 1.0987x over previous
//
#include <hip/hip_runtime.h>

#define HH_DIM 2048
#define WW_DIM 2048
#define NF 64
#define MAX_DEPTH 12
#define NBLK 16            // build blocks; each owns 256 of the 4096 paths
#define SEG 8192           // items per block segment (safe upper bound)
#define CHUNK 2048         // target pixels per item

// Item encoding:
//   word0 = x0 | y0<<12 | idx<<24   (x0,y0 <= 2047; idx <= 63)
//   word1 = w | h<<12               (w,h <= 2048)
__device__ __forceinline__ uint2 enc(int x0, int y0, int idx, int w, int h) {
    return make_uint2((unsigned)x0 | ((unsigned)y0 << 12) | ((unsigned)idx << 24),
                      (unsigned)w | ((unsigned)h << 12));
}

__device__ __forceinline__ unsigned wave_iscan(unsigned x, int lane) {
    #pragma unroll
    for (int off = 1; off < 64; off <<= 1) {
        unsigned v = __shfl_up(x, off);
        if (lane >= off) x += v;
    }
    return x;
}

// Kernel A: path-parallel leaf enumeration (proven in round 5). Thread j
// descends the 12-bit path j; leaves survive only along the all-left
// extension, so each leaf is emitted by exactly one thread. Block b
// compacts its row-chunk items into segment b with count cnt[b].
__global__ __launch_bounds__(256)
void build_kernel(const float* __restrict__ sel,     // [NF,2,NF]
                  const float* __restrict__ ratios,  // [NF]
                  int* __restrict__ cnt,             // [NBLK]
                  uint2* __restrict__ items) {       // [NBLK*SEG]
    __shared__ float s_ratio[NF];
    __shared__ int   s_child[2 * NF];
    __shared__ int   s_items;

    int t = threadIdx.x;
    int lane = t & 63;

    if (t < 2 * NF) {                     // first-max argmax (strict >)
        const float* row = sel + t * NF;
        float best = row[0]; int bi = 0;
        #pragma unroll
        for (int j = 1; j < NF; ++j) { float v = row[j]; if (v > best) { best = v; bi = j; } }
        s_child[t] = bi;
    }
    if (t < NF) s_ratio[t] = ratios[t];
    if (t == 0) s_items = 0;
    __syncthreads();

    int j = (blockIdx.x << 8) + t;        // path id, 0..4095
    int x0 = 0, y0 = 0, w = WW_DIM, h = HH_DIM, idx = 0;
    bool alive = true;
    #pragma unroll
    for (int d = 0; d < MAX_DEPTH; ++d) {
        int bit = (j >> (11 - d)) & 1;
        if (w < 2 || h < 2) {             // leaf: survives only all-left
            if (bit) { alive = false; break; }
            continue;
        }
        float ratio = s_ratio[idx];
        if (idx & 1) {                    // vertical split
            int lw = (int)floorf((float)w * ratio); if (lw < 1) lw = 1;
            if (bit == 0) { w = lw; } else { x0 += lw; w -= lw; }
        } else {                          // horizontal split
            int th = (int)floorf((float)h * ratio); if (th < 1) th = 1;
            if (bit == 0) { h = th; } else { y0 += th; h -= th; }
        }
        idx = bit ? s_child[2 * idx + 1] : s_child[2 * idx];
    }

    unsigned nit = 0;
    int rpc = 1;
    if (alive) {
        rpc = CHUNK / w; if (rpc < 1) rpc = 1;     // rows per chunk
        nit = (unsigned)((h + rpc - 1) / rpc);
    }

    unsigned inc = wave_iscan(nit, lane);
    unsigned tot = __shfl(inc, 63);
    int base = 0;
    if (lane == 63 && tot) base = atomicAdd(&s_items, (int)tot);
    base = __shfl(base, 63);
    int s = base + (int)(inc - nit);

    uint2* seg = items + blockIdx.x * SEG;
    if (nit) {
        int nn = (int)nit;
        for (int k = 0; k < nn; ++k) {
            int r0 = k * rpc;
            int hc = h - r0; if (hc > rpc) hc = rpc;
            if (s + k < SEG) seg[s + k] = enc(x0, y0 + r0, idx, w, hc);
        }
    }
    __syncthreads();
    if (t == 0) cnt[blockIdx.x] = (s_items < SEG) ? s_items : SEG;
}

// Kernel B: paint frame-idx bytes into the 4 MB map. 1 B/px instead of
// 12 B/px -> 12x less scattered traffic; exact-count iteration via a
// 16-entry prefix over segment counts (no empty-slot scanning).
__global__ __launch_bounds__(256)
void paint_kernel(const int* __restrict__ cnt,       // [NBLK]
                  const uint2* __restrict__ items,   // [NBLK*SEG]
                  unsigned char* __restrict__ map) { // [H*W]
    int pre[NBLK];
    int total = 0;
    #pragma unroll
    for (int s = 0; s < NBLK; ++s) { pre[s] = total; total += cnt[s]; }

    for (int r = blockIdx.x; r < total; r += gridDim.x) {
        int sg = 0;
        #pragma unroll
        for (int s = 1; s < NBLK; ++s) if (r >= pre[s]) sg = s;
        uint2 v = items[sg * SEG + (r - pre[sg])];
        int x0 = (int)(v.x & 0xFFF), y0 = (int)((v.x >> 12) & 0xFFF);
        unsigned char idx = (unsigned char)(v.x >> 24);
        int w = (int)(v.y & 0xFFF), hc = (int)((v.y >> 12) & 0xFFF);
        int n = w * hc;                               // <= CHUNK
        float rw = 1.0f / (float)w;
        for (int p = threadIdx.x; p < n; p += 256) {
            int rr = (int)((float)p * rw);            // +-1, fixed below
            int c = p - rr * w;
            if (c < 0)       { rr -= 1; c += w; }
            else if (c >= w) { rr += 1; c -= w; }
            map[(y0 + rr) * WW_DIM + x0 + c] = idx;
        }
    }
}

// Kernel C: streaming colorize. Read 4 px of map per lane (u32, coalesced),
// LDS color lookup, write three float4 streams (fully coalesced 50 MB).
__global__ __launch_bounds__(256)
void colorize_kernel(const float* __restrict__ colors,     // [NF,3]
                     const unsigned char* __restrict__ map,
                     float* __restrict__ out) {            // [3,H,W]
    __shared__ float s_r[NF], s_g[NF], s_b[NF];
    int t = threadIdx.x;
    if (t < NF) {
        s_r[t] = colors[3 * t];
        s_g[t] = colors[3 * t + 1];
        s_b[t] = colors[3 * t + 2];
    }
    __syncthreads();

    int gid = blockIdx.x * 256 + t;            // 1,048,576 threads, 4 px each
    unsigned m4 = *(const unsigned*)(map + gid * 4);
    int i0 = (int)(m4 & 0xFF), i1 = (int)((m4 >> 8) & 0xFF);
    int i2 = (int)((m4 >> 16) & 0xFF), i3 = (int)(m4 >> 24);

    int base = gid * 4;
    const int plane = HH_DIM * WW_DIM;
    *(float4*)(out + base)             = make_float4(s_r[i0], s_r[i1], s_r[i2], s_r[i3]);
    *(float4*)(out + plane + base)     = make_float4(s_g[i0], s_g[i1], s_g[i2], s_g[i3]);
    *(float4*)(out + 2 * plane + base) = make_float4(s_b[i0], s_b[i1], s_b[i2], s_b[i3]);
}

extern "C" void kernel_launch(void* const* d_in, const int* in_sizes, int n_in,
                              void* d_out, int out_size, void* d_ws, size_t ws_size,
                              hipStream_t stream) {
    const float* frame_colors    = (const float*)d_in[0];  // [64,3]
    const float* frame_selection = (const float*)d_in[1];  // [64,2,64]
    const float* split_ratios    = (const float*)d_in[2];  // [64]
    float* out = (float*)d_out;

    int*           cnt   = (int*)d_ws;                               // 64 B
    uint2*         items = (uint2*)((char*)d_ws + 1024);             // 1 MB
    unsigned char* map   = (unsigned char*)((char*)d_ws + (2 << 20)); // 4 MB

    build_kernel<<<NBLK, 256, 0, stream>>>(frame_selection, split_ratios,
                                           cnt, items);
    paint_kernel<<<4096, 256, 0, stream>>>(cnt, items, map);
    colorize_kernel<<<4096, 256, 0, stream>>>(frame_colors, map, out);
}

// Round 7
// 99.285 us; speedup vs baseline: 1.4275x; 1.0080x over previous
//
#include <hip/hip_runtime.h>

#define HH_DIM 2048
#define WW_DIM 2048
#define NF 64
#define MAX_DEPTH 12
#define NBLK 16            // build blocks; each owns 256 of the 4096 paths
#define SEG 8192           // items per block segment (safe upper bound)
#define CHUNK 2048         // target pixels per item

// Item encoding:
//   word0 = x0 | y0<<12 | idx<<24   (x0,y0 <= 2047; idx <= 63)
//   word1 = w | h<<12               (w,h <= 2048)
__device__ __forceinline__ uint2 enc(int x0, int y0, int idx, int w, int h) {
    return make_uint2((unsigned)x0 | ((unsigned)y0 << 12) | ((unsigned)idx << 24),
                      (unsigned)w | ((unsigned)h << 12));
}

__device__ __forceinline__ unsigned wave_iscan(unsigned x, int lane) {
    #pragma unroll
    for (int off = 1; off < 64; off <<= 1) {
        unsigned v = __shfl_up(x, off);
        if (lane >= off) x += v;
    }
    return x;
}

// Kernel A: path-parallel leaf enumeration (proven rounds 5-6). Thread j
// descends the 12-bit path j; a leaf survives only along the all-left
// extension, so each leaf is emitted by exactly one thread. Block b
// compacts its row-chunk items into segment b with count cnt[b].
__global__ __launch_bounds__(256)
void build_kernel(const float* __restrict__ sel,     // [NF,2,NF]
                  const float* __restrict__ ratios,  // [NF]
                  int* __restrict__ cnt,             // [NBLK]
                  uint2* __restrict__ items) {       // [NBLK*SEG]
    __shared__ float s_ratio[NF];
    __shared__ int   s_child[2 * NF];
    __shared__ int   s_items;

    int t = threadIdx.x;
    int lane = t & 63;

    if (t < 2 * NF) {                     // first-max argmax (strict >)
        const float* row = sel + t * NF;
        float best = row[0]; int bi = 0;
        #pragma unroll
        for (int j = 1; j < NF; ++j) { float v = row[j]; if (v > best) { best = v; bi = j; } }
        s_child[t] = bi;
    }
    if (t < NF) s_ratio[t] = ratios[t];
    if (t == 0) s_items = 0;
    __syncthreads();

    int j = (blockIdx.x << 8) + t;        // path id, 0..4095
    int x0 = 0, y0 = 0, w = WW_DIM, h = HH_DIM, idx = 0;
    bool alive = true;
    #pragma unroll
    for (int d = 0; d < MAX_DEPTH; ++d) {
        int bit = (j >> (11 - d)) & 1;
        if (w < 2 || h < 2) {             // leaf: survives only all-left
            if (bit) { alive = false; break; }
            continue;
        }
        float ratio = s_ratio[idx];
        if (idx & 1) {                    // vertical split
            int lw = (int)floorf((float)w * ratio); if (lw < 1) lw = 1;
            if (bit == 0) { w = lw; } else { x0 += lw; w -= lw; }
        } else {                          // horizontal split
            int th = (int)floorf((float)h * ratio); if (th < 1) th = 1;
            if (bit == 0) { h = th; } else { y0 += th; h -= th; }
        }
        idx = bit ? s_child[2 * idx + 1] : s_child[2 * idx];
    }

    unsigned nit = 0;
    int rpc = 1;
    if (alive) {
        rpc = CHUNK / w; if (rpc < 1) rpc = 1;     // rows per chunk
        nit = (unsigned)((h + rpc - 1) / rpc);
    }

    unsigned inc = wave_iscan(nit, lane);
    unsigned tot = __shfl(inc, 63);
    int base = 0;
    if (lane == 63 && tot) base = atomicAdd(&s_items, (int)tot);
    base = __shfl(base, 63);
    int s = base + (int)(inc - nit);

    uint2* seg = items + blockIdx.x * SEG;
    if (nit) {
        int nn = (int)nit;
        for (int k = 0; k < nn; ++k) {
            int r0 = k * rpc;
            int hc = h - r0; if (hc > rpc) hc = rpc;
            if (s + k < SEG) seg[s + k] = enc(x0, y0 + r0, idx, w, hc);
        }
    }
    __syncthreads();
    if (t == 0) cnt[blockIdx.x] = (s_items < SEG) ? s_items : SEG;
}

// Kernel B: paint frame-idx bytes into the 4 MB map (1 B/px). Exact-count
// iteration via a 16-entry prefix over segment counts; grid sized to the
// real item population (~2-6K items) to cut the idle-block tail.
__global__ __launch_bounds__(256)
void paint_kernel(const int* __restrict__ cnt,       // [NBLK]
                  const uint2* __restrict__ items,   // [NBLK*SEG]
                  unsigned char* __restrict__ map) { // [H*W]
    int pre[NBLK];
    int total = 0;
    #pragma unroll
    for (int s = 0; s < NBLK; ++s) { pre[s] = total; total += cnt[s]; }

    for (int r = blockIdx.x; r < total; r += gridDim.x) {
        int sg = 0;
        #pragma unroll
        for (int s = 1; s < NBLK; ++s) if (r >= pre[s]) sg = s;
        uint2 v = items[sg * SEG + (r - pre[sg])];
        int x0 = (int)(v.x & 0xFFF), y0 = (int)((v.x >> 12) & 0xFFF);
        unsigned char idx = (unsigned char)(v.x >> 24);
        int w = (int)(v.y & 0xFFF), hc = (int)((v.y >> 12) & 0xFFF);
        int n = w * hc;                               // <= CHUNK
        float rw = 1.0f / (float)w;
        for (int p = threadIdx.x; p < n; p += 256) {
            int rr = (int)((float)p * rw);            // +-1, fixed below
            int c = p - rr * w;
            if (c < 0)       { rr -= 1; c += w; }
            else if (c >= w) { rr += 1; c -= w; }
            map[(y0 + rr) * WW_DIM + x0 + c] = idx;
        }
    }
}

// Kernel C: streaming colorize. Read 4 px of map per lane (u32, coalesced),
// LDS color lookup, write three float4 streams (fully coalesced 50 MB).
// Issue cost ~0.4 us; BW floor ~10 us -> already at the roofline for this
// phase.
__global__ __launch_bounds__(256)
void colorize_kernel(const float* __restrict__ colors,     // [NF,3]
                     const unsigned char* __restrict__ map,
                     float* __restrict__ out) {            // [3,H,W]
    __shared__ float s_r[NF], s_g[NF], s_b[NF];
    int t = threadIdx.x;
    if (t < NF) {
        s_r[t] = colors[3 * t];
        s_g[t] = colors[3 * t + 1];
        s_b[t] = colors[3 * t + 2];
    }
    __syncthreads();

    int gid = blockIdx.x * 256 + t;            // 1,048,576 threads, 4 px each
    unsigned m4 = *(const unsigned*)(map + gid * 4);
    int i0 = (int)(m4 & 0xFF), i1 = (int)((m4 >> 8) & 0xFF);
    int i2 = (int)((m4 >> 16) & 0xFF), i3 = (int)(m4 >> 24);

    int base = gid * 4;
    const int plane = HH_DIM * WW_DIM;
    *(float4*)(out + base)             = make_float4(s_r[i0], s_r[i1], s_r[i2], s_r[i3]);
    *(float4*)(out + plane + base)     = make_float4(s_g[i0], s_g[i1], s_g[i2], s_g[i3]);
    *(float4*)(out + 2 * plane + base) = make_float4(s_b[i0], s_b[i1], s_b[i2], s_b[i3]);
}

extern "C" void kernel_launch(void* const* d_in, const int* in_sizes, int n_in,
                              void* d_out, int out_size, void* d_ws, size_t ws_size,
                              hipStream_t stream) {
    const float* frame_colors    = (const float*)d_in[0];  // [64,3]
    const float* frame_selection = (const float*)d_in[1];  // [64,2,64]
    const float* split_ratios    = (const float*)d_in[2];  // [64]
    float* out = (float*)d_out;

    int*           cnt   = (int*)d_ws;                               // 64 B
    uint2*         items = (uint2*)((char*)d_ws + 1024);             // 1 MB
    unsigned char* map   = (unsigned char*)((char*)d_ws + (2 << 20)); // 4 MB

    build_kernel<<<NBLK, 256, 0, stream>>>(frame_selection, split_ratios,
                                           cnt, items);
    paint_kernel<<<2048, 256, 0, stream>>>(cnt, items, map);
    colorize_kernel<<<4096, 256, 0, stream>>>(frame_colors, map, out);
}

// Round 9
// 95.109 us; speedup vs baseline: 1.4902x; 1.0439x over previous
//
#include <hip/hip_runtime.h>

#define HH_DIM 2048
#define WW_DIM 2048
#define NF 64
#define MAX_DEPTH 12

// Native clang vector type: __builtin_nontemporal_store requires it
// (HIP_vector_type<float,4> is a struct and is rejected).
typedef float nt4 __attribute__((ext_vector_type(4)));

// Kernel 1: build packed node + color tables in workspace.
//   node[f]  = float2{ ratio[f], int(left_child | right_child << 16) }
//   cpack[f] = float4{ r, g, b, 0 }
// First-max semantics (strict >) to match jnp.argmax.
__global__ void prep_kernel(const float* __restrict__ sel,     // [NF,2,NF]
                            const float* __restrict__ ratios,  // [NF]
                            const float* __restrict__ colors,  // [NF,3]
                            float2* __restrict__ node,         // [NF]
                            float4* __restrict__ cpack) {      // [NF]
    __shared__ int s_child[2 * NF];
    int t = threadIdx.x;
    if (t < 2 * NF) {
        const float* row = sel + t * NF;
        float best = row[0];
        int bi = 0;
        #pragma unroll
        for (int j = 1; j < NF; ++j) {
            float v = row[j];
            if (v > best) { best = v; bi = j; }
        }
        s_child[t] = bi;
    }
    __syncthreads();
    if (t < NF) {
        int packed = s_child[2 * t] | (s_child[2 * t + 1] << 16);
        node[t] = make_float2(ratios[t], __int_as_float(packed));
        cpack[t] = make_float4(colors[3 * t], colors[3 * t + 1], colors[3 * t + 2], 0.0f);
    }
}

// Kernel 2 (round-2 best-measured structure): fully branchless lockstep
// descent. 4 consecutive x-pixels per thread, each descending MAX_DEPTH
// levels unconditionally via cndmask selects (zero divergent branches).
// Geometry in f32: all quantities are exact small integers, so
// floorf/compare/sub are exact and results match the int reference
// bit-for-bit. Leaf states are absorbing (limiting dimension stays at 1),
// so guarding only idx suffices. Descent issue (~11.5 us) overlaps the
// 50 MB store stream (~8.5 us) across waves -> near max(), not sum.
__global__ __launch_bounds__(256)
void render_kernel(const float2* __restrict__ node,
                   const float4* __restrict__ cpack,
                   float* __restrict__ out) {                  // [3,H,W]
    __shared__ float2 s_node[NF];
    __shared__ float4 s_col[NF];

    int t = threadIdx.x;
    if (t < NF)            s_node[t] = node[t];
    else if (t < 2 * NF)   s_col[t - NF] = cpack[t - NF];
    __syncthreads();

    int gid = blockIdx.x * 256 + t;           // 1,048,576 threads
    int y  = gid >> 9;                         // 512 groups of 4 px per row
    int xb = (gid & 511) << 2;

    int   idx[4];
    float rx[4], ry[4], w[4], h[4];
    #pragma unroll
    for (int p = 0; p < 4; ++p) {
        idx[p] = 0;
        rx[p] = (float)(xb + p);
        ry[p] = (float)y;
        w[p]  = (float)WW_DIM;
        h[p]  = (float)HH_DIM;
    }

    #pragma unroll
    for (int d = 0; d < MAX_DEPTH; ++d) {
        #pragma unroll
        for (int p = 0; p < 4; ++p) {
            float2 nd = s_node[idx[p]];        // one ds_read_b64
            int   pk  = __float_as_int(nd.y);
            bool  vert = (idx[p] & 1) != 0;
            float cs = vert ? w[p]  : h[p];
            float rc = vert ? rx[p] : ry[p];
            float ls = floorf(cs * nd.x);      // exact: ints < 2^24
            ls = fmaxf(ls, 1.0f);
            bool left = rc < ls;
            int  child = (pk >> (left ? 0 : 16)) & 63;
            bool act = fminf(w[p], h[p]) >= 2.0f;
            idx[p] = act ? child : idx[p];
            float rc2 = left ? rc : rc - ls;   // exact int sub
            float ns  = left ? ls : cs - ls;
            rx[p] = vert ? rc2  : rx[p];
            ry[p] = vert ? ry[p] : rc2;
            w[p]  = vert ? ns   : w[p];
            h[p]  = vert ? h[p] : ns;
        }
    }

    float4 k0 = s_col[idx[0]];
    float4 k1 = s_col[idx[1]];
    float4 k2 = s_col[idx[2]];
    float4 k3 = s_col[idx[3]];

    int base = y * WW_DIM + xb;
    const int plane = HH_DIM * WW_DIM;
    // Output is write-once, never re-read: nontemporal stores keep the
    // 50 MB stream from churning L2.
    nt4 v0 = { k0.x, k1.x, k2.x, k3.x };
    nt4 v1 = { k0.y, k1.y, k2.y, k3.y };
    nt4 v2 = { k0.z, k1.z, k2.z, k3.z };
    __builtin_nontemporal_store(v0, (nt4*)(out + base));
    __builtin_nontemporal_store(v1, (nt4*)(out + plane + base));
    __builtin_nontemporal_store(v2, (nt4*)(out + 2 * plane + base));
}

extern "C" void kernel_launch(void* const* d_in, const int* in_sizes, int n_in,
                              void* d_out, int out_size, void* d_ws, size_t ws_size,
                              hipStream_t stream) {
    const float* frame_colors    = (const float*)d_in[0];  // [64,3]
    const float* frame_selection = (const float*)d_in[1];  // [64,2,64]
    const float* split_ratios    = (const float*)d_in[2];  // [64]
    float* out = (float*)d_out;

    float2* node  = (float2*)d_ws;                 // 64 * 8 B
    float4* cpack = (float4*)((char*)d_ws + 1024); // 64 * 16 B (aligned)

    prep_kernel<<<1, 128, 0, stream>>>(frame_selection, split_ratios,
                                       frame_colors, node, cpack);
    render_kernel<<<4096, 256, 0, stream>>>(node, cpack, out);
}